// Round 10
// baseline (3717.320 us; speedup 1.0000x reference)
//
#include <hip/hip_runtime.h>

typedef unsigned short u16;
typedef unsigned int   u32;
typedef unsigned long long u64;
typedef __attribute__((ext_vector_type(8))) short bf16x8;
typedef __attribute__((ext_vector_type(16))) float f32x16;
typedef __attribute__((ext_vector_type(4))) float f32x4;
typedef __attribute__((ext_vector_type(4))) u32 u32x4;

#define T_SEQ 300

// workspace layout (bytes) — all offsets 16B-aligned
#define OFF_WP   0u            // packed A-frag weights bf16: 256 jp * 42 kk * 64 lanes * 16B = 11,010,048
#define OFF_BP   11010048u     // packed bias f32 [512 j][16 g] = 32,768
#define OFF_XB   11042816u     // x bf16 K-slot layout: 300*128*192*2 = 14,745,600
#define OFF_H    25788416u     // h arena bf16: 301 * 128*512 * 2B = 39,452,672

__device__ __forceinline__ float bf2f(u16 u){ union { u32 u; float f; } v; v.u = ((u32)u) << 16; return v.f; }
__device__ __forceinline__ u16 f2bf(float f){
  union { float f; u32 u; } v; v.f = f;
  u32 r = v.u + 0x7fffu + ((v.u >> 16) & 1u);
  return (u16)(r >> 16);
}
__device__ __forceinline__ float sigf(float x){ return 1.f / (1.f + __expf(-x)); }
__device__ __forceinline__ float tanh_f(float x){ return 1.f - 2.f / (1.f + __expf(2.f * x)); }

// Sentinel protocol: h-arena slots for steps 1..300 are pre-filled with
// 0xFFFF (= bf16 NaN, unreachable: h = sigmoid*tanh of finite inputs, and
// f2bf round-to-nearest-even of a finite float never yields NaN). A fragment
// is its own readiness flag — no flags, no grid barriers, no __syncthreads
// in the recurrence loop. Detect "any u16 == 0xFFFF" via zero-u16 trick.
__device__ __forceinline__ bool has_sent(u64 x){
  u64 y = ~x;
  return ((y - 0x0001000100010001ull) & ~y & 0x8000800080008000ull) != 0ull;
}

union HF { u64 q[2]; u32x4 u; bf16x8 v; };

// Proven-progress primitive (r5/r9): agent-scope relaxed atomic load observes
// remote agent-scope atomic stores even when re-polling one address.
__device__ __forceinline__ u64 ald(const u64* p){
  return __hip_atomic_load(p, __ATOMIC_RELAXED, __HIP_MEMORY_SCOPE_AGENT);
}

// ---------------------------------------------------------------------------
// prep: pack fp32 weights into 32x32x16 MFMA A-operand fragments (gates on the
// M side; acc[reg] = gate reg for j=jp*2+(lane>>5) per lane). Bias pack
// [j][16]. Zero h step 0; fill h steps 1..300 with sentinel 0xFFFF.
// ---------------------------------------------------------------------------
__global__ void prep(const float* __restrict__ Wx, const float* __restrict__ Wh,
                     const float* __restrict__ bg, const float* __restrict__ Wxo,
                     const float* __restrict__ Who, const float* __restrict__ bo,
                     u16* __restrict__ Wp, float* __restrict__ bpack,
                     u16* __restrict__ h0)
{
  int w = blockIdx.x * 256 + threadIdx.x;     // 0 .. 688127 = 256 jp * 42 kk * 64

  if (w < 8192) {
    u32x4 z = {0u, 0u, 0u, 0u};
    ((u32x4*)h0)[w] = z;                      // zero h[0] (128*512 bf16)
    int j = w >> 4, g = w & 15;
    float bv;
    if (g < 15) { int p = g / 3, t3 = g - p * 3; bv = bg[p * 1536 + t3 * 512 + j]; }
    else bv = bo[j];
    bpack[w] = bv;
  }
  // sentinel-fill steps 1..300: 300 * 8192 16B-chunks
  {
    u32x4 s = {~0u, ~0u, ~0u, ~0u};
    u32x4* base = (u32x4*)(h0 + 65536);
    for (u32 idx = w; idx < 300u * 8192u; idx += 688128u) base[idx] = s;
  }

  int lane = w & 63, rem = w >> 6;
  int kk = rem % 42, jp = rem / 42;           // jp 0..255
  int m = lane & 31, hi = lane >> 5;
  int jj = (m >> 2) & 1, g = (m & 3) + 4 * (m >> 3);
  int j = jp * 2 + jj;
  union { u16 s[8]; u32x4 v; } o;
  #pragma unroll
  for (int i = 0; i < 8; ++i) {
    int k = kk * 16 + hi * 8 + i;
    float val = 0.f;
    if (g < 15) {
      int p = g / 3, t3 = g - p * 3, col = t3 * 512 + j;
      if (k < 512) val = Wh[(p * 512 + k) * 1536 + col];
      else {
        int s = k - 512, px = s >> 5, cc = (s >> 3) & 3, ii = s & 7;
        int d = (cc < 3) ? cc * 8 + ii : ((ii < 2) ? -1 : 22 + ii);
        if (px == p && d >= 0) val = Wx[(p * 30 + d) * 1536 + col];
      }
    } else {
      if (k < 512) val = Who[k * 512 + j];
      else {
        int s = k - 512, px = s >> 5, cc = (s >> 3) & 3, ii = s & 7;
        int d = (cc < 3) ? cc * 8 + ii : ((ii < 2) ? -1 : 22 + ii);
        if (d >= 0) val = Wxo[(px * 30 + d) * 512 + j];
      }
    }
    o.s[i] = f2bf(val);
  }
  *(u32x4*)(Wp + ((size_t)(jp * 42 + kk) * 64 + lane) * 8) = o.v;
}

// prep_x: fp32 x [5][128][300][30] -> bf16 xb[t][bglob][slot] (slot 0..191,
// slots 160..191 zero pad). One thread = one 8-slot chunk (16B store).
__global__ void prep_x(const float* __restrict__ x, u16* __restrict__ xb)
{
  int w = blockIdx.x * 256 + threadIdx.x;     // 0 .. 921599
  int cx = w % 24, rem = w / 24;
  int bglob = rem % 128, t = rem / 128;
  union { u16 s[8]; u32x4 v; } o;
  int s0 = cx << 3;
  if (s0 >= 160) {
    u32x4 z = {0u, 0u, 0u, 0u}; o.v = z;
  } else {
    int p = s0 >> 5, cc = (s0 >> 3) & 3;
    const float* row = x + ((size_t)(p * 128 + bglob) * 300 + t) * 30;
    #pragma unroll
    for (int i = 0; i < 8; ++i) {
      int d = (cc < 3) ? cc * 8 + i : 22 + i;
      o.s[i] = f2bf(row[d]);
    }
  }
  *(u32x4*)(xb + (size_t)w * 8) = o.v;
}

// ---------------------------------------------------------------------------
// Persistent part-LSTM — wave-autonomous, zero-barrier recurrence.
// 128 blocks x 512 threads (cooperative, proven co-resident). Wave (bq,jp):
// M=32 (16 gates x 2 j), N=32 batch rows, K=672; weights register-resident.
// Per step: x B-frags direct from global (plain, L1-shared across the block's
// waves) -> 10 x-MFMAs; then 32 h-MFMAs with 4-deep plain-load prefetch ring
// + sentinel check + atomic-retry fallback; per-lane elementwise; immediate
// per-wave publish (shfl_xor pair -> 32 agent-scope u32 stores). No
// __syncthreads, no flags: K-step kk consumes exactly the j-columns published
// by the block jgh=kk of the same quarter, readiness carried in the data.
// ---------------------------------------------------------------------------
__global__ void __launch_bounds__(512, 2)
plstm(const u16* __restrict__ xb, const u16* __restrict__ Wp,
      const float* __restrict__ bpack, u16* hall,
      const float* __restrict__ fcw, const float* __restrict__ fcb,
      float* __restrict__ out)
{
  const int tid  = threadIdx.x;
  const int lane = tid & 63;
  const int wv   = tid >> 6;          // 8 waves
  const int n    = lane & 31;         // batch row within quarter
  const int hi   = lane >> 5;         // k-half / j-parity
  const int bq   = blockIdx.x >> 5;   // 0..3
  const int jgh  = blockIdx.x & 31;   // 0..31 (16 j each)
  const int jp   = jgh * 8 + wv;      // j-pair 0..255
  const int j    = jp * 2 + hi;       // this lane's hidden col

  // resident A-fragments (weights), 42 ksteps x 4 regs
  bf16x8 afr[42];
  {
    const u16* wpb = Wp + ((size_t)jp * 42 * 64 + lane) * 8;
    #pragma unroll
    for (int kk = 0; kk < 42; ++kk)
      afr[kk] = *(const bf16x8*)(wpb + kk * 512);
  }
  float bias[16];
  #pragma unroll
  for (int i = 0; i < 4; ++i)
    *(f32x4*)(bias + i * 4) = *(const f32x4*)(bpack + j * 16 + i * 4);

  float cst[5] = {0.f, 0.f, 0.f, 0.f, 0.f};

  for (int t = 0; t < T_SEQ; ++t) {
    f32x16 acc;
    #pragma unroll
    for (int i = 0; i < 16; ++i) acc[i] = 0.f;

    // ---- h B-frag base for this lane (16B per kk, stride 32B) ----
    const u16* hb = hall + (size_t)t * 65536 + (size_t)(bq * 32 + n) * 512 + hi * 8;

    // prefetch ring: plain loads (L1-cacheable; all 8 waves share lines)
    u32x4 pf0 = *(const u32x4*)(hb);
    u32x4 pf1 = *(const u32x4*)(hb + 16);
    u32x4 pf2 = *(const u32x4*)(hb + 32);
    u32x4 pf3 = *(const u32x4*)(hb + 48);

    // ---- x part first (no h dependency; gives producers time) ----
    {
      const u16* xl = xb + (size_t)(t * 128 + bq * 32 + n) * 192 + hi * 8;
      #pragma unroll
      for (int kx = 0; kx < 10; ++kx) {
        bf16x8 bf = *(const bf16x8*)(xl + kx * 16);
        acc = __builtin_amdgcn_mfma_f32_32x32x16_bf16(afr[32 + kx], bf, acc, 0, 0, 0);
      }
    }

    // ---- K-loop, hidden part: consume ring, sentinel-check, atomic retry ----
    #pragma unroll
    for (int kk = 0; kk < 32; ++kk) {
      HF f;
      f.u = (kk & 3) == 0 ? pf0 : (kk & 3) == 1 ? pf1 : (kk & 3) == 2 ? pf2 : pf3;
      if (kk + 4 < 32) {
        u32x4 nv = *(const u32x4*)(hb + (kk + 4) * 16);
        if ((kk & 3) == 0) pf0 = nv; else if ((kk & 3) == 1) pf1 = nv;
        else if ((kk & 3) == 2) pf2 = nv; else pf3 = nv;
      }
      while (has_sent(f.q[0])) f.q[0] = ald((const u64*)(hb + kk * 16));
      while (has_sent(f.q[1])) f.q[1] = ald((const u64*)(hb + kk * 16 + 4));
      acc = __builtin_amdgcn_mfma_f32_32x32x16_bf16(afr[kk], f.v, acc, 0, 0, 0);
    }

    // ---- per-lane elementwise: acc[g] = gate g for (j, b) ----
    float cs = 0.f;
    #pragma unroll
    for (int p = 0; p < 5; ++p) {
      float iv = acc[p * 3 + 0] + bias[p * 3 + 0];
      float fv = acc[p * 3 + 1] + bias[p * 3 + 1];
      float gv = acc[p * 3 + 2] + bias[p * 3 + 2];
      cst[p] = sigf(fv) * cst[p] + sigf(iv) * tanh_f(gv);
      cs += cst[p];
    }
    float hv = sigf(acc[15] + bias[15]) * tanh_f(cs);

    // ---- immediate per-wave publish: pair j/j+1 via shfl_xor(32) ----
    u16 own = f2bf(hv);
    int other = __shfl_xor((int)own, 32);
    if (hi == 0) {
      u32 val = (u32)own | ((u32)(u16)other << 16);
      u32* dst = (u32*)(hall + (size_t)(t + 1) * 65536
                        + (size_t)(bq * 32 + n) * 512 + jp * 2);
      __hip_atomic_store(dst, val, __ATOMIC_RELAXED, __HIP_MEMORY_SCOPE_AGENT);
    }
  }

  // ---- classifier + log_softmax: blocks 0..63 do 2 batch rows each ----
  if (blockIdx.x >= 64) return;
  __shared__ __align__(16) u16 Hc[2 * 512];
  __shared__ float fsh[640];
  const u16* hT = hall + (size_t)T_SEQ * 65536 + (size_t)(blockIdx.x * 2) * 512;
  if (tid < 128) {                       // sentinel-retry stage 2 rows (2 KB)
    const u16* p = hT + ((tid >> 6) << 9) + ((tid & 63) << 3);
    HF f; f.u = *(const u32x4*)p;
    while (has_sent(f.q[0])) f.q[0] = ald((const u64*)p);
    while (has_sent(f.q[1])) f.q[1] = ald((const u64*)(p + 4));
    *(u32x4*)(Hc + tid * 8) = f.u;
  }
  __syncthreads();
  for (int r = 0; r < 2; ++r) {
    int row = blockIdx.x * 2 + r;
    int ks = tid >> 6, c = tid & 63;     // 8 K-slices of 64
    float s = 0.f;
    if (c < 60) {
      const u16* hr = Hc + (r << 9) + ks * 64;
      const float* wr = fcw + (size_t)(ks * 64) * 60 + c;
      #pragma unroll 8
      for (int k = 0; k < 64; ++k) s += bf2f(hr[k]) * wr[k * 60];
    }
    __syncthreads();
    fsh[ks * 64 + c] = s;
    __syncthreads();
    if (tid < 60) {
      float lg = fcb[tid];
      #pragma unroll
      for (int i = 0; i < 8; ++i) lg += fsh[i * 64 + tid];
      fsh[512 + tid] = lg;
    }
    __syncthreads();
    if (tid == 0) {
      float mx = -1e30f;
      for (int i = 0; i < 60; ++i) mx = fmaxf(mx, fsh[512 + i]);
      float sm = 0.f;
      for (int i = 0; i < 60; ++i) sm += __expf(fsh[512 + i] - mx);
      fsh[576] = mx + __logf(sm);
    }
    __syncthreads();
    if (tid < 60) out[row * 60 + tid] = fsh[512 + tid] - fsh[576];
    __syncthreads();
  }
}

extern "C" void kernel_launch(void* const* d_in, const int* in_sizes, int n_in,
                              void* d_out, int out_size, void* d_ws, size_t ws_size,
                              hipStream_t stream)
{
  const float* xin = (const float*)d_in[0];   // [5][128][300][30]
  const float* Wx  = (const float*)d_in[1];   // [5][30][1536]
  const float* Wh  = (const float*)d_in[2];   // [5][512][1536]
  const float* bg  = (const float*)d_in[3];   // [5][1536]
  const float* Wxo = (const float*)d_in[4];   // [150][512]
  const float* Who = (const float*)d_in[5];   // [512][512]
  const float* bo  = (const float*)d_in[6];   // [512]
  const float* fcw = (const float*)d_in[7];   // [512][60]
  const float* fcb = (const float*)d_in[8];   // [60]
  float* out = (float*)d_out;                 // [128][60]

  char* ws = (char*)d_ws;
  u16*   Wp    = (u16*)(ws + OFF_WP);
  float* bpack = (float*)(ws + OFF_BP);
  u16*   xb    = (u16*)(ws + OFF_XB);
  u16*   hall  = (u16*)(ws + OFF_H);

  hipLaunchKernelGGL(prep, dim3(2688), dim3(256), 0, stream,
                     Wx, Wh, bg, Wxo, Who, bo, Wp, bpack, hall);
  hipLaunchKernelGGL(prep_x, dim3(3600), dim3(256), 0, stream, xin, xb);

  void* args[] = { (void*)&xb, (void*)&Wp, (void*)&bpack, (void*)&hall,
                   (void*)&fcw, (void*)&fcb, (void*)&out };
  hipLaunchCooperativeKernel((void*)plstm, dim3(128), dim3(512), args, 0, stream);
}